// Round 8
// baseline (330.876 us; speedup 1.0000x reference)
//
#include <hip/hip_runtime.h>
#include <math.h>

// Problem geometry (fixed by setup_inputs)
#define NN 2
#define DD 160
#define HH 192
#define WW 160
#define DO 154   // DD-6
#define HO 186   // HH-6
#define WO 154   // WW-6

#define NWO 3    // wo tiles of 64
#define NHO 47   // ho tiles of 4
#define ZCH 8    // z chunks
#define ZOC 20   // ceil(DO/ZCH)
#define NB (NWO * NHO * NN * ZCH)   // 2256 blocks

// LDS-only barrier: s_waitcnt lgkmcnt(0) (vmcnt left outstanding) + s_barrier.
// Global prefetch loads stay in flight across the barrier (CK block_sync_lds).
#define LDS_SYNC() do { __builtin_amdgcn_s_waitcnt(0xC07F); __builtin_amdgcn_s_barrier(); } while (0)

__device__ __forceinline__ unsigned mono_f2u(float f) {
  unsigned u = __float_as_uint(f);
  return (u & 0x80000000u) ? ~u : (u | 0x80000000u);
}

__device__ __forceinline__ float block_sum(float v, float* sm) {
  int tid = threadIdx.x;
  sm[tid] = v;
  __syncthreads();
#pragma unroll
  for (int off = 128; off > 0; off >>= 1) {
    if (tid < off) sm[tid] += sm[tid + off];
    __syncthreads();
  }
  float r = sm[0];
  __syncthreads();
  return r;
}

__device__ __forceinline__ float block_min(float v, float* sm) {
  int tid = threadIdx.x;
  sm[tid] = v;
  __syncthreads();
#pragma unroll
  for (int off = 128; off > 0; off >>= 1) {
    if (tid < off) sm[tid] = fminf(sm[tid], sm[tid + off]);
    __syncthreads();
  }
  float r = sm[0];
  __syncthreads();
  return r;
}

// acc layout (floats): [0..3] = snv, sn, sv, cnt (zeroed);
// [4] = vmin monotone-uint (init 0xFFFFFFFF); [5] = arrival counter (zeroed).
__global__ __launch_bounds__(256, 6) void ncc_fused(const float* __restrict__ X,
                                                    const float* __restrict__ Y,
                                                    float* __restrict__ acc,
                                                    float* __restrict__ out) {
  __shared__ __align__(16) float R[5][10][64];   // 12.8 KB W-filtered moment rows
  __shared__ __align__(16) float Mh[5][4][64];   // 5 KB   W+H-filtered moments
  __shared__ float sm[256];

  const int tid = threadIdx.x;
  const int tx = tid & 63, ty = tid >> 6;
  const int wo0 = blockIdx.x * 64;
  const int ho0 = blockIdx.y * 4;
  const int n   = blockIdx.z >> 3;   // ZCH == 8
  const int ck  = blockIdx.z & 7;
  const int z0  = ck * ZOC;
  const int zout = min(ZOC, DO - z0);
  const int nslice = zout + 6;

  const int wo = wo0 + tx, ho = ho0 + ty;
  const bool act = (wo < WO) && (ho < HO);

  const size_t slice = (size_t)HH * WW;
  const float* Xn = X + (size_t)n * DD * slice;
  const float* Yn = Y + (size_t)n * DD * slice;
  const float inv_nw = 1.0f / 343.0f;
  const float LO = -1.0f - 1e-5f, HI = 1.0f + 1e-5f;

  // Phase-A quad item: 160 items, item p -> row r=p>>4 (0..9), cols cq..cq+3.
  const int pA  = tid;
  const bool hasA = (pA < 160);
  const int rA  = pA >> 4;
  const int cqA = (pA & 15) << 2;
  const int hA  = ho0 + rA;
  const int baseW = wo0 + cqA;                 // multiple of 4, <=152 when valid
  const bool okA  = hasA && (hA < HH) && (baseW < WO);
  const bool tail = okA && (baseW + 9 >= WW);  // last float2 would cross the row
  const float* XrowA = Xn + (size_t)hA * WW + baseW;
  const float* YrowA = Yn + (size_t)hA * WW + baseW;

  float4 lx0 = {0,0,0,0}, lx1 = {0,0,0,0}, ly0 = {0,0,0,0}, ly1 = {0,0,0,0};
  float2 lx2 = {0,0}, ly2 = {0,0};

  auto loadA = [&](int s_in) {
    if (okA) {
      const float* xp = XrowA + (size_t)(z0 + s_in) * slice;
      const float* yp = YrowA + (size_t)(z0 + s_in) * slice;
      lx0 = *(const float4*)xp; lx1 = *(const float4*)(xp + 4);
      ly0 = *(const float4*)yp; ly1 = *(const float4*)(yp + 4);
      if (!tail) { lx2 = *(const float2*)(xp + 8); ly2 = *(const float2*)(yp + 8); }
      else       { lx2 = make_float2(0.f, 0.f);    ly2 = make_float2(0.f, 0.f); }
    }
  };

  auto storeA = [&]() {
    if (okA) {
      float x0=lx0.x,x1=lx0.y,x2=lx0.z,x3=lx0.w,x4=lx1.x,x5=lx1.y,x6=lx1.z,x7=lx1.w,x8=lx2.x,x9=lx2.y;
      float y0=ly0.x,y1=ly0.y,y2=ly0.z,y3=ly0.w,y4=ly1.x,y5=ly1.y,y6=ly1.z,y7=ly1.w,y8=ly2.x,y9=ly2.y;
      {
        float a = x0+x1+x2+x3+x4+x5+x6;
        float b = a - x0 + x7, c = b - x1 + x8, d = c - x2 + x9;
        *(float4*)&R[0][rA][cqA] = make_float4(a, b, c, d);
      }
      {
        float a = y0+y1+y2+y3+y4+y5+y6;
        float b = a - y0 + y7, c = b - y1 + y8, d = c - y2 + y9;
        *(float4*)&R[1][rA][cqA] = make_float4(a, b, c, d);
      }
      {
        float a = x0*x0+x1*x1+x2*x2+x3*x3+x4*x4+x5*x5+x6*x6;
        float b = a - x0*x0 + x7*x7, c = b - x1*x1 + x8*x8, d = c - x2*x2 + x9*x9;
        *(float4*)&R[2][rA][cqA] = make_float4(a, b, c, d);
      }
      {
        float a = y0*y0+y1*y1+y2*y2+y3*y3+y4*y4+y5*y5+y6*y6;
        float b = a - y0*y0 + y7*y7, c = b - y1*y1 + y8*y8, d = c - y2*y2 + y9*y9;
        *(float4*)&R[3][rA][cqA] = make_float4(a, b, c, d);
      }
      {
        float a = x0*y0+x1*y1+x2*y2+x3*y3+x4*y4+x5*y5+x6*y6;
        float b = a - x0*y0 + x7*y7, c = b - x1*y1 + x8*y8, d = c - x2*y2 + x9*y9;
        *(float4*)&R[4][rA][cqA] = make_float4(a, b, c, d);
      }
    }
  };

  // Phase H: incremental 7-tap H-sums (10 reads -> 4 outputs per (ch,wo)).
  // Items 0..255: ch=ty. Items 256..319 (ch=4): mapped to wave 3 only
  // (tid 192..255) so the extra work runs at full 64-lane density.
  auto phaseH = [&]() {
    {
      const int ch = ty, w = tx;
      const float* rp = &R[ch][0][w];
      float r0=rp[0],r1=rp[64],r2=rp[128],r3=rp[192],r4=rp[256],
            r5=rp[320],r6=rp[384],r7=rp[448],r8=rp[512],r9=rp[576];
      float m0 = r0+r1+r2+r3+r4+r5+r6;
      float m1 = m0 - r0 + r7, m2 = m1 - r1 + r8, m3 = m2 - r2 + r9;
      Mh[ch][0][w]=m0; Mh[ch][1][w]=m1; Mh[ch][2][w]=m2; Mh[ch][3][w]=m3;
    }
    if (tid >= 192) {
      const int w = tid - 192;
      const float* rp = &R[4][0][w];
      float r0=rp[0],r1=rp[64],r2=rp[128],r3=rp[192],r4=rp[256],
            r5=rp[320],r6=rp[384],r7=rp[448],r8=rp[512],r9=rp[576];
      float m0 = r0+r1+r2+r3+r4+r5+r6;
      float m1 = m0 - r0 + r7, m2 = m1 - r1 + r8, m3 = m2 - r2 + r9;
      Mh[4][0][w]=m0; Mh[4][1][w]=m1; Mh[4][2][w]=m2; Mh[4][3][w]=m3;
    }
  };

  // Rotating 7-phase accumulators (no ring storage, no shift movs).
  float a0[7], a1[7], a2[7], a3[7], a4[7];
#pragma unroll
  for (int j = 0; j < 7; ++j) { a0[j]=0.f; a1[j]=0.f; a2[j]=0.f; a3[j]=0.f; a4[j]=0.f; }
  float p_snv = 0.f, p_sn = 0.f, p_sv = 0.f, p_cnt = 0.f, p_vmin = 3.4e38f;

  loadA(0);
  storeA();
  __syncthreads();

  for (int sb = 0; sb < nslice; sb += 7) {
#pragma unroll
    for (int u = 0; u < 7; ++u) {
      const int s = sb + u;
      if (s < nslice) {                       // wave-uniform
        if (s + 1 < nslice) loadA(s + 1);     // global -> regs (stays in flight)
        phaseH();                             // R -> Mh
        LDS_SYNC();
        {                                      // Phase O: Mh -> accumulators
          float m0 = Mh[0][ty][tx], m1 = Mh[1][ty][tx], m2 = Mh[2][ty][tx],
                m3 = Mh[3][ty][tx], m4 = Mh[4][ty][tx];
#pragma unroll
          for (int j = 0; j < 7; ++j) {
            a0[j]+=m0; a1[j]+=m1; a2[j]+=m2; a3[j]+=m3; a4[j]+=m4;
          }
          if (s >= 6 && act) {
            float zs0=a0[u], zs1=a1[u], zs2=a2[u], zs3=a3[u], zs4=a4[u];
            float num = zs4 - zs0 * zs1 * inv_nw;
            float d0  = zs2 - zs0 * zs0 * inv_nw;
            float d1  = zs3 - zs1 * zs1 * inv_nw;
            float den = d0 * d1;
            if (den > 1e-5f) {
              float ncc = num * __frsqrt_rn(den);
              if (ncc >= LO && ncc <= HI) {
                float v = 0.5f * (d0 + d1);
                p_snv += ncc * v; p_sn += ncc; p_sv += v; p_cnt += 1.f;
                p_vmin = fminf(p_vmin, v);
              }
            }
          }
          a0[u]=0.f; a1[u]=0.f; a2[u]=0.f; a3[u]=0.f; a4[u]=0.f;
        }
        if (s + 1 < nslice) storeA();         // vmcnt wait lands HERE
        LDS_SYNC();
      }
    }
  }

  // ---- block reduce, global atomics, last-block finalize ----
  float bsnv = block_sum(p_snv, sm);
  float bsn  = block_sum(p_sn, sm);
  float bsv  = block_sum(p_sv, sm);
  float bcnt = block_sum(p_cnt, sm);
  float bmin = block_min(p_vmin, sm);
  if (tid == 0) {
    atomicAdd(&acc[0], bsnv);
    atomicAdd(&acc[1], bsn);
    atomicAdd(&acc[2], bsv);
    atomicAdd(&acc[3], bcnt);
    atomicMin((unsigned*)acc + 4, mono_f2u(bmin));
    __threadfence();
    unsigned prev = atomicAdd((unsigned*)acc + 5, 1u);
    if (prev == NB - 1) {
      // last block: read back via no-op RMW atomics (device-scope coherent)
      float snv = atomicAdd(&acc[0], 0.f);
      float sn  = atomicAdd(&acc[1], 0.f);
      float sv  = atomicAdd(&acc[2], 0.f);
      float cnt = atomicAdd(&acc[3], 0.f);
      unsigned um = atomicMin((unsigned*)acc + 4, 0xFFFFFFFFu);
      unsigned bits = (um & 0x80000000u) ? (um ^ 0x80000000u) : ~um;
      float vmin = __uint_as_float(bits);
      // loss = 1 - (S_nv - vmin*S_n)/(S_v - vmin*cnt); min-max scale cancels.
      out[0] = 1.0f - (snv - vmin * sn) / (sv - vmin * cnt);
    }
  }
}

extern "C" void kernel_launch(void* const* d_in, const int* in_sizes, int n_in,
                              void* d_out, int out_size, void* d_ws, size_t ws_size,
                              hipStream_t stream) {
  const float* X = (const float*)d_in[0];  // y_pred
  const float* Y = (const float*)d_in[1];  // y_true
  // d_in[2]: ones kernel, constant, unused.

  float* acc = (float*)d_ws;
  // [0..3]=sums:0, [4]=vmin-mono:0xFFFFFFFF, [5]=counter:0
  hipMemsetAsync(acc, 0, 16, stream);
  hipMemsetAsync((char*)acc + 16, 0xFF, 4, stream);
  hipMemsetAsync((char*)acc + 20, 0, 4, stream);

  dim3 g(NWO, NHO, NN * ZCH);
  ncc_fused<<<g, 256, 0, stream>>>(X, Y, acc, (float*)d_out);
}

// Round 9
// 305.202 us; speedup vs baseline: 1.0841x; 1.0841x over previous
//
#include <hip/hip_runtime.h>
#include <math.h>

// Problem geometry (fixed by setup_inputs)
#define NN 2
#define DD 160
#define HH 192
#define WW 160
#define DO 154   // DD-6
#define HO 186   // HH-6
#define WO 154   // WW-6

#define NWO 3    // wo tiles of 64
#define NHO 47   // ho tiles of 4
#define ZCH 8    // z chunks
#define ZOC 20   // ceil(DO/ZCH)
#define NB (NWO * NHO * NN * ZCH)   // 2256 blocks

// LDS-only barrier: s_waitcnt lgkmcnt(0) (vmcnt left outstanding) + s_barrier.
// Global prefetch loads stay in flight across the barrier (CK block_sync_lds).
#define LDS_SYNC() do { __builtin_amdgcn_s_waitcnt(0xC07F); __builtin_amdgcn_s_barrier(); } while (0)

__device__ __forceinline__ unsigned mono_f2u(float f) {
  unsigned u = __float_as_uint(f);
  return (u & 0x80000000u) ? ~u : (u | 0x80000000u);
}

__device__ __forceinline__ float block_sum(float v, float* sm) {
  int tid = threadIdx.x;
  sm[tid] = v;
  __syncthreads();
#pragma unroll
  for (int off = 128; off > 0; off >>= 1) {
    if (tid < off) sm[tid] += sm[tid + off];
    __syncthreads();
  }
  float r = sm[0];
  __syncthreads();
  return r;
}

__device__ __forceinline__ float block_min(float v, float* sm) {
  int tid = threadIdx.x;
  sm[tid] = v;
  __syncthreads();
#pragma unroll
  for (int off = 128; off > 0; off >>= 1) {
    if (tid < off) sm[tid] = fminf(sm[tid], sm[tid + off]);
    __syncthreads();
  }
  float r = sm[0];
  __syncthreads();
  return r;
}

struct Ld {
  float4 x0, x1, y0, y1;
  float2 x2, y2;
};

// acc layout (floats): [0..3] = snv, sn, sv, cnt (zeroed);
// [4] = vmin monotone-uint (init 0xFFFFFFFF); [5] = arrival counter (zeroed).
__global__ __launch_bounds__(256, 4) void ncc_fused(const float* __restrict__ X,
                                                    const float* __restrict__ Y,
                                                    float* __restrict__ acc,
                                                    float* __restrict__ out) {
  // Parity-split buffers: index 0 = even slices, 1 = odd slices.
  __shared__ __align__(16) float R[2][5][10][64];   // 25.6 KB W-filtered moment rows
  __shared__ __align__(16) float Mh[2][5][4][64];   // 10 KB   W+H-filtered moments
  __shared__ float sm[256];

  const int tid = threadIdx.x;
  const int tx = tid & 63, ty = tid >> 6;
  const int wo0 = blockIdx.x * 64;
  const int ho0 = blockIdx.y * 4;
  const int n   = blockIdx.z >> 3;   // ZCH == 8
  const int ck  = blockIdx.z & 7;
  const int z0  = ck * ZOC;
  const int zout = min(ZOC, DO - z0);
  const int nslice = zout + 6;       // 26 or 20 — always even

  const int wo = wo0 + tx, ho = ho0 + ty;
  const bool act = (wo < WO) && (ho < HO);

  const size_t slice = (size_t)HH * WW;
  const float* Xn = X + (size_t)n * DD * slice;
  const float* Yn = Y + (size_t)n * DD * slice;
  const float inv_nw = 1.0f / 343.0f;
  const float LO = -1.0f - 1e-5f, HI = 1.0f + 1e-5f;

  // Phase-A quad item: 160 items, item p -> row r=p>>4 (0..9), cols cq..cq+3.
  const int pA  = tid;
  const bool hasA = (pA < 160);
  const int rA  = pA >> 4;
  const int cqA = (pA & 15) << 2;
  const int hA  = ho0 + rA;
  const int baseW = wo0 + cqA;                 // multiple of 4, <=152 when valid
  const bool okA  = hasA && (hA < HH) && (baseW < WO);
  const bool tail = okA && (baseW + 9 >= WW);  // last float2 would cross the row
  const float* XrowA = Xn + (size_t)hA * WW + baseW;
  const float* YrowA = Yn + (size_t)hA * WW + baseW;

  auto loadA = [&](int s_in, Ld& L) {
    if (okA) {
      const float* xp = XrowA + (size_t)(z0 + s_in) * slice;
      const float* yp = YrowA + (size_t)(z0 + s_in) * slice;
      L.x0 = *(const float4*)xp; L.x1 = *(const float4*)(xp + 4);
      L.y0 = *(const float4*)yp; L.y1 = *(const float4*)(yp + 4);
      if (!tail) { L.x2 = *(const float2*)(xp + 8); L.y2 = *(const float2*)(yp + 8); }
      else       { L.x2 = make_float2(0.f, 0.f);    L.y2 = make_float2(0.f, 0.f); }
    }
  };

  auto storeA = [&](const Ld& L, int buf) {
    if (okA) {
      float x0=L.x0.x,x1=L.x0.y,x2=L.x0.z,x3=L.x0.w,x4=L.x1.x,x5=L.x1.y,x6=L.x1.z,x7=L.x1.w,x8=L.x2.x,x9=L.x2.y;
      float y0=L.y0.x,y1=L.y0.y,y2=L.y0.z,y3=L.y0.w,y4=L.y1.x,y5=L.y1.y,y6=L.y1.z,y7=L.y1.w,y8=L.y2.x,y9=L.y2.y;
      {
        float a = x0+x1+x2+x3+x4+x5+x6;
        float b = a - x0 + x7, c = b - x1 + x8, d = c - x2 + x9;
        *(float4*)&R[buf][0][rA][cqA] = make_float4(a, b, c, d);
      }
      {
        float a = y0+y1+y2+y3+y4+y5+y6;
        float b = a - y0 + y7, c = b - y1 + y8, d = c - y2 + y9;
        *(float4*)&R[buf][1][rA][cqA] = make_float4(a, b, c, d);
      }
      {
        float a = x0*x0+x1*x1+x2*x2+x3*x3+x4*x4+x5*x5+x6*x6;
        float b = a - x0*x0 + x7*x7, c = b - x1*x1 + x8*x8, d = c - x2*x2 + x9*x9;
        *(float4*)&R[buf][2][rA][cqA] = make_float4(a, b, c, d);
      }
      {
        float a = y0*y0+y1*y1+y2*y2+y3*y3+y4*y4+y5*y5+y6*y6;
        float b = a - y0*y0 + y7*y7, c = b - y1*y1 + y8*y8, d = c - y2*y2 + y9*y9;
        *(float4*)&R[buf][3][rA][cqA] = make_float4(a, b, c, d);
      }
      {
        float a = x0*y0+x1*y1+x2*y2+x3*y3+x4*y4+x5*y5+x6*y6;
        float b = a - x0*y0 + x7*y7, c = b - x1*y1 + x8*y8, d = c - x2*y2 + x9*y9;
        *(float4*)&R[buf][4][rA][cqA] = make_float4(a, b, c, d);
      }
    }
  };

  // Phase H: incremental 7-tap H-sums (10 reads -> 4 outputs per (ch,wo)).
  // Items 0..255: ch=ty. Items for ch=4 run on wave 3 at full lane density.
  auto phaseH = [&](int buf) {
    {
      const int ch = ty, w = tx;
      const float* rp = &R[buf][ch][0][w];
      float r0=rp[0],r1=rp[64],r2=rp[128],r3=rp[192],r4=rp[256],
            r5=rp[320],r6=rp[384],r7=rp[448],r8=rp[512],r9=rp[576];
      float m0 = r0+r1+r2+r3+r4+r5+r6;
      float m1 = m0 - r0 + r7, m2 = m1 - r1 + r8, m3 = m2 - r2 + r9;
      Mh[buf][ch][0][w]=m0; Mh[buf][ch][1][w]=m1; Mh[buf][ch][2][w]=m2; Mh[buf][ch][3][w]=m3;
    }
    if (tid >= 192) {
      const int w = tid - 192;
      const float* rp = &R[buf][4][0][w];
      float r0=rp[0],r1=rp[64],r2=rp[128],r3=rp[192],r4=rp[256],
            r5=rp[320],r6=rp[384],r7=rp[448],r8=rp[512],r9=rp[576];
      float m0 = r0+r1+r2+r3+r4+r5+r6;
      float m1 = m0 - r0 + r7, m2 = m1 - r1 + r8, m3 = m2 - r2 + r9;
      Mh[buf][4][0][w]=m0; Mh[buf][4][1][w]=m1; Mh[buf][4][2][w]=m2; Mh[buf][4][3][w]=m3;
    }
  };

  // Rotating 7-phase accumulators (compile-time indexed via unroll-14 loop).
  float a0[7], a1[7], a2[7], a3[7], a4[7];
#pragma unroll
  for (int j = 0; j < 7; ++j) { a0[j]=0.f; a1[j]=0.f; a2[j]=0.f; a3[j]=0.f; a4[j]=0.f; }
  float p_snv = 0.f, p_sn = 0.f, p_sv = 0.f, p_cnt = 0.f, p_vmin = 3.4e38f;

  auto phaseO = [&](int buf, int s, int u) {
    float m0 = Mh[buf][0][ty][tx], m1 = Mh[buf][1][ty][tx], m2 = Mh[buf][2][ty][tx],
          m3 = Mh[buf][3][ty][tx], m4 = Mh[buf][4][ty][tx];
#pragma unroll
    for (int j = 0; j < 7; ++j) {
      a0[j]+=m0; a1[j]+=m1; a2[j]+=m2; a3[j]+=m3; a4[j]+=m4;
    }
    if (s >= 6 && act) {
      float zs0=a0[u], zs1=a1[u], zs2=a2[u], zs3=a3[u], zs4=a4[u];
      float num = zs4 - zs0 * zs1 * inv_nw;
      float d0  = zs2 - zs0 * zs0 * inv_nw;
      float d1  = zs3 - zs1 * zs1 * inv_nw;
      float den = d0 * d1;
      if (den > 1e-5f) {
        float ncc = num * __frsqrt_rn(den);
        if (ncc >= LO && ncc <= HI) {
          float v = 0.5f * (d0 + d1);
          p_snv += ncc * v; p_sn += ncc; p_sv += v; p_cnt += 1.f;
          p_vmin = fminf(p_vmin, v);
        }
      }
    }
    a0[u]=0.f; a1[u]=0.f; a2[u]=0.f; a3[u]=0.f; a4[u]=0.f;
  };

  Ld LA, LB;
  // Prologue: slices 0 (even -> buf 0) and 1 (odd -> buf 1).
  loadA(0, LA); loadA(1, LB);
  storeA(LA, 0); storeA(LB, 1);
  __syncthreads();

  // Pair-processing: 2 slices per barrier region; unroll 14 (= lcm(2,7)) so
  // the 7-phase index u = s % 7 is compile-time (14 % 7 == 0 across regions).
  for (int sb = 0; sb < nslice; sb += 14) {
#pragma unroll
    for (int p = 0; p < 7; ++p) {
      const int s0 = sb + 2 * p;
      const int s1 = s0 + 1;
      if (s0 < nslice) {                      // block-uniform
        const bool n0 = (s0 + 2 < nslice);
        const bool n1 = (s0 + 3 < nslice);
        if (n0) loadA(s0 + 2, LA);            // global -> regs, stays in flight
        if (n1) loadA(s0 + 3, LB);
        phaseH(0);                            // H(s0): R[0] -> Mh[0]
        phaseH(1);                            // H(s1): R[1] -> Mh[1] (s1<nslice always: nslice even)
        LDS_SYNC();
        phaseO(0, s0, (2 * p) % 7);
        phaseO(1, s1, (2 * p + 1) % 7);
        if (n0) storeA(LA, 0);                // vmcnt waits land HERE
        if (n1) storeA(LB, 1);
        LDS_SYNC();
      }
    }
  }

  // ---- block reduce, global atomics, last-block finalize ----
  float bsnv = block_sum(p_snv, sm);
  float bsn  = block_sum(p_sn, sm);
  float bsv  = block_sum(p_sv, sm);
  float bcnt = block_sum(p_cnt, sm);
  float bmin = block_min(p_vmin, sm);
  if (tid == 0) {
    atomicAdd(&acc[0], bsnv);
    atomicAdd(&acc[1], bsn);
    atomicAdd(&acc[2], bsv);
    atomicAdd(&acc[3], bcnt);
    atomicMin((unsigned*)acc + 4, mono_f2u(bmin));
    __threadfence();
    unsigned prev = atomicAdd((unsigned*)acc + 5, 1u);
    if (prev == NB - 1) {
      // last block: read back via no-op RMW atomics (device-scope coherent)
      float snv = atomicAdd(&acc[0], 0.f);
      float sn  = atomicAdd(&acc[1], 0.f);
      float sv  = atomicAdd(&acc[2], 0.f);
      float cnt = atomicAdd(&acc[3], 0.f);
      unsigned um = atomicMin((unsigned*)acc + 4, 0xFFFFFFFFu);
      unsigned bits = (um & 0x80000000u) ? (um ^ 0x80000000u) : ~um;
      float vmin = __uint_as_float(bits);
      // loss = 1 - (S_nv - vmin*S_n)/(S_v - vmin*cnt); min-max scale cancels.
      out[0] = 1.0f - (snv - vmin * sn) / (sv - vmin * cnt);
    }
  }
}

extern "C" void kernel_launch(void* const* d_in, const int* in_sizes, int n_in,
                              void* d_out, int out_size, void* d_ws, size_t ws_size,
                              hipStream_t stream) {
  const float* X = (const float*)d_in[0];  // y_pred
  const float* Y = (const float*)d_in[1];  // y_true
  // d_in[2]: ones kernel, constant, unused.

  float* acc = (float*)d_ws;
  // [0..3]=sums:0, [4]=vmin-mono:0xFFFFFFFF, [5]=counter:0
  hipMemsetAsync(acc, 0, 16, stream);
  hipMemsetAsync((char*)acc + 16, 0xFF, 4, stream);
  hipMemsetAsync((char*)acc + 20, 0, 4, stream);

  dim3 g(NWO, NHO, NN * ZCH);
  ncc_fused<<<g, 256, 0, stream>>>(X, Y, acc, (float*)d_out);
}